// Round 8
// baseline (843.699 us; speedup 1.0000x reference)
//
#include <hip/hip_runtime.h>

#define S_LEN 2048
#define NB 2
#define NH 32
#define NKV 8
#define HD 128
#define HID 4096
#define NQKV 6144

using bf16x8 = __attribute__((ext_vector_type(8))) __bf16;
using f32x4  = __attribute__((ext_vector_type(4))) float;

__device__ __forceinline__ ushort f2b(float f) {
  uint u = __builtin_bit_cast(uint, f);
  u += 0x7fffu + ((u >> 16) & 1u);
  return (ushort)(u >> 16);
}
__device__ __forceinline__ float b2f(ushort h) {
  uint u = ((uint)h) << 16;
  return __builtin_bit_cast(float, u);
}

__device__ __forceinline__ uint cvt_pk_bf16(float lo, float hi) {
  uint r;
  asm("v_cvt_pk_bf16_f32 %0, %1, %2" : "=v"(r) : "v"(lo), "v"(hi));
  return r;
}

__device__ __forceinline__ void gld16(const void* g, void* l) {
  __builtin_amdgcn_global_load_lds((const __attribute__((address_space(1))) void*)g,
                                   (__attribute__((address_space(3))) void*)l, 16, 0, 0);
}

__device__ __forceinline__ void stc(float* C, size_t i, float v)  { C[i] = v; }
__device__ __forceinline__ void stc(ushort* C, size_t i, float v) { C[i] = f2b(v); }

// ---------------- f32 -> bf16 elementwise ----------------
__global__ void cvt_bf16(const float* __restrict__ src, ushort* __restrict__ dst, int n) {
  int i = (blockIdx.x * 256 + threadIdx.x) * 4;
  if (i < n) {
    float4 v = *(const float4*)(src + i);
    *(ushort4*)(dst + i) = make_ushort4(f2b(v.x), f2b(v.y), f2b(v.z), f2b(v.w));
  }
}

// ---------------- f32 [R][C] -> bf16 [C][R] transpose (padded tile, conflict-free) ----
__global__ void trans_f32_bf16(const float* __restrict__ src, ushort* __restrict__ dst,
                               int R, int C) {
  __shared__ float tile[32][33];
  const int c0 = blockIdx.x * 32, r0 = blockIdx.y * 32;
  const int x = threadIdx.x, y = threadIdx.y;  // block (32,8)
#pragma unroll
  for (int i = 0; i < 32; i += 8)
    tile[y + i][x] = src[(size_t)(r0 + y + i) * C + (c0 + x)];
  __syncthreads();
#pragma unroll
  for (int i = 0; i < 32; i += 8)
    dst[(size_t)(c0 + y + i) * R + (r0 + x)] = f2b(tile[x][y + i]);
}

// ================= pipelined 128x256 bf16 NT GEMM (ring-2, BK=32, v3) =================
// C[M][N] = A[M][K] * Bt[N][K]^T. 256 threads = 4 waves laid 1M x 4N; wave tile
// 128x64 (acc[8][4] = 128 VGPR). RATIONALE (R7 counters): conflicts=0 and
// MfmaUtil 41% => LDS read BW is the binding resource. Wave tile 128x64 costs
// 12 ds_read_b128 per 32 MFMA (0.375 reads/MFMA) vs 64x64's 8/16 (0.5) — a 25%
// cut in LDS traffic per FLOP. A-panel (128x32) is read by all 4 waves
// (same-address broadcast, free); B-panel 256 wide, each wave owns 64 cols.
// LDS 48 KiB: ring-2 of A[128][32] + B[256][32]; rows of 4 16B-chunks, slot s
// of row r holds k-chunk s^(r&3) (same zero-conflict family as R7, both-sides
// per rule #21: linear gld16 dest + inverse-swizzled global source).
// Schedule per K=32 tile (R5/R7-proven): stage t+1 (6 gld16/thread) ->
// vmcnt(6) (wait tile t, keep 6 in flight) -> s_barrier -> 12 ds_read + 32
// MFMA -> s_barrier.
template <typename OutT>
__global__ __launch_bounds__(256, 2) void gemm_p3(const ushort* __restrict__ A,
                                                  const ushort* __restrict__ Bt,
                                                  OutT* __restrict__ C,
                                                  int M, int Ncol, int K,
                                                  int lda, int ldb) {
  __shared__ ushort As[2][128 * 32];
  __shared__ ushort Bs[2][256 * 32];
  const int tid = threadIdx.x, wave = tid >> 6, lane = tid & 63;
  const int lr = lane & 15, lg = lane >> 4;
  const int wn = wave;  // 4 waves across N
  const int m0 = blockIdx.y * 128, n0 = blockIdx.x * 256;

  f32x4 acc[8][4];
#pragma unroll
  for (int i = 0; i < 8; ++i)
#pragma unroll
    for (int j = 0; j < 4; ++j) acc[i][j] = (f32x4){0.f, 0.f, 0.f, 0.f};

  const int NT = K >> 5;

  // stage one K=32 tile: A 512 chunks (2/thread) + B 1024 chunks (4/thread)
  auto stage = [&](int kt, int bufi) {
#pragma unroll
    for (int it = 0; it < 2; ++it) {
      const int cb = it * 256 + wave * 64;  // wave-uniform chunk base
      const int c = cb + lane;
      const int row = c >> 2, kc = (c & 3) ^ (row & 3);
      gld16(A + (size_t)(m0 + row) * lda + kt + kc * 8, &As[bufi][cb * 8]);
    }
#pragma unroll
    for (int it = 0; it < 4; ++it) {
      const int cb = it * 256 + wave * 64;
      const int c = cb + lane;
      const int row = c >> 2, kc = (c & 3) ^ (row & 3);
      gld16(Bt + (size_t)(n0 + row) * ldb + kt + kc * 8, &Bs[bufi][cb * 8]);
    }
  };

  stage(0, 0);

  for (int it = 0; it < NT; ++it) {
    const int buf = it & 1;
    if (it + 1 < NT) {
      stage((it + 1) << 5, buf ^ 1);
      asm volatile("s_waitcnt vmcnt(6)" ::: "memory");  // tile it landed
    } else {
      asm volatile("s_waitcnt vmcnt(0)" ::: "memory");
    }
    asm volatile("s_barrier" ::: "memory");

    bf16x8 af[8], bfr[4];
#pragma unroll
    for (int f = 0; f < 8; ++f) {
      const int row = f * 16 + lr;
      af[f] = *(const bf16x8*)(&As[buf][row * 32 + ((lg ^ (lr & 3)) << 3)]);
    }
#pragma unroll
    for (int g = 0; g < 4; ++g) {
      const int row = wn * 64 + g * 16 + lr;
      bfr[g] = *(const bf16x8*)(&Bs[buf][row * 32 + ((lg ^ (lr & 3)) << 3)]);
    }
    __builtin_amdgcn_s_setprio(1);
#pragma unroll
    for (int f = 0; f < 8; ++f)
#pragma unroll
      for (int g = 0; g < 4; ++g)
        acc[f][g] = __builtin_amdgcn_mfma_f32_16x16x32_bf16(af[f], bfr[g], acc[f][g], 0, 0, 0);
    __builtin_amdgcn_s_setprio(0);

    asm volatile("s_barrier" ::: "memory");  // all waves done reading buf
  }

  // epilogue: per-wave 128x64 C sub-tile
#pragma unroll
  for (int f = 0; f < 8; ++f)
#pragma unroll
    for (int g = 0; g < 4; ++g)
#pragma unroll
      for (int r = 0; r < 4; ++r) {
        const int row = m0 + f * 16 + lg * 4 + r;
        const int col = n0 + wn * 64 + g * 16 + lr;
        stc(C, (size_t)row * Ncol + col, acc[f][g][r]);
      }
}

// ---------------- RoPE in-place on q/k heads of qkv (bf16) ----------------
__global__ __launch_bounds__(256) void rope_qk(ushort* __restrict__ qkv) {
  int t = blockIdx.x * 256 + threadIdx.x;
  const int i = t & 63;
  t >>= 6;
  const int head  = t % (NH + NKV);
  const int token = t / (NH + NKV);
  const int s = token & (S_LEN - 1);
  const size_t base = (size_t)token * NQKV + (head < NH ? head * HD : HID + (head - NH) * HD);
  const float x1 = b2f(qkv[base + i]);
  const float x2 = b2f(qkv[base + 64 + i]);
  const float invf = exp2f(-(float)i * 0.2076205059304602f);  // 10000^(-i/64)
  const float fr = (float)s * invf;
  float cs, sn;
  sincosf(fr, &sn, &cs);  // sincosf writes SIN first, COS second
  float o1 = x1 * cs - x2 * sn;
  float o2 = x2 * cs + x1 * sn;
  if (head < NH) {
    o1 *= 0.08838834764831845f;  // 1/sqrt(128) pre-applied to Q
    o2 *= 0.08838834764831845f;
  }
  qkv[base + i]      = f2b(o1);
  qkv[base + 64 + i] = f2b(o2);
}

// ---------------- V: qkv[token][5120+kv*128+d] -> Vt[b*8+kv][d][s] ----------------
__global__ void vtrans(const ushort* __restrict__ qkv, ushort* __restrict__ Vt) {
  __shared__ ushort tile[32][33];
  const int dt = blockIdx.x * 32, st = blockIdx.y * 32, bk = blockIdx.z;
  const int b = bk >> 3, kv = bk & 7;
  const int x = threadIdx.x, y = threadIdx.y;  // (32,8)
#pragma unroll
  for (int i = 0; i < 32; i += 8)
    tile[y + i][x] =
        qkv[(size_t)(b * S_LEN + st + y + i) * NQKV + 5120 + kv * HD + dt + x];
  __syncthreads();
#pragma unroll
  for (int i = 0; i < 32; i += 8)
    Vt[((size_t)bk * HD + dt + y + i) * S_LEN + st + x] = tile[x][y + i];
}

// ---------------- flash attention v5 (unchanged from passing R7) ----------------
__global__ __launch_bounds__(256) void attn_fa(ushort* __restrict__ qkv,
                                               const ushort* __restrict__ Vt) {
  const int lin = blockIdx.x + 32 * blockIdx.y + 256 * blockIdx.z;
  const int swz = (lin & 7) * 64 + (lin >> 3);
  const int qp = swz & 31;
  const int g  = swz >> 5;
  const int kvh = g & 7;
  const int b   = g >> 3;

  const int wid  = threadIdx.x >> 6;
  const int lane = threadIdx.x & 63;
  const int lr = lane & 15, lg = lane >> 4;
  const int h  = kvh * 4 + wid;

  const ushort* K = qkv + (size_t)(b * S_LEN) * NQKV + HID + kvh * HD;
  const ushort* V = Vt + (size_t)(b * NKV + kvh) * (HD * S_LEN);

  __shared__ ushort Ks[2][32 * 128];   // 8 KB per buf
  __shared__ ushort Vs[2][128 * 32];   // 8 KB per buf
  __shared__ ushort P[4][16 * 40];     // per-wave private P tile

  for (int seg = 0; seg < 2; ++seg) {
    const int qt = seg ? (63 - qp) : qp;
    const int q0 = qt * 32;
    const ushort* Q = qkv + (size_t)(b * S_LEN + q0) * NQKV + h * HD;

    bf16x8 qf[2][4];
#pragma unroll
    for (int t = 0; t < 2; ++t)
#pragma unroll
      for (int kb = 0; kb < 4; ++kb)
        qf[t][kb] = *(const bf16x8*)(Q + (size_t)(t * 16 + lr) * NQKV + kb * 32 + lg * 8);

    f32x4 o[2][8];
#pragma unroll
    for (int t = 0; t < 2; ++t)
#pragma unroll
      for (int c = 0; c < 8; ++c) o[t][c] = (f32x4){0.f, 0.f, 0.f, 0.f};
    float mi[2]  = {-1e30f, -1e30f};
    float lip[2] = {0.f, 0.f};

    const int NTk = qt + 1;  // uniform across the block

    // prologue: stage tile 0 (4 gld16/wave: 2 K + 2 V)
#pragma unroll
    for (int it = 0; it < 2; ++it) {
      const int cb = it * 256 + wid * 64;
      const int d = cb + lane;
      const int krow = d >> 4, kslot = d & 15;
      gld16(K + (size_t)krow * NQKV + ((kslot ^ (krow & 15)) * 8), &Ks[0][cb * 8]);
      const int vrow = d >> 2, vslot = d & 3;
      gld16(V + (size_t)vrow * S_LEN + ((vslot ^ ((vrow >> 1) & 3)) * 8), &Vs[0][cb * 8]);
    }

    for (int itk = 0; itk < NTk; ++itk) {
      const int k0 = itk << 5;
      const int bufi = itk & 1;
      if (itk + 1 < NTk) {
        const int kn = k0 + 32;
#pragma unroll
        for (int it = 0; it < 2; ++it) {
          const int cb = it * 256 + wid * 64;
          const int d = cb + lane;
          const int krow = d >> 4, kslot = d & 15;
          gld16(K + (size_t)(kn + krow) * NQKV + ((kslot ^ (krow & 15)) * 8),
                &Ks[bufi ^ 1][cb * 8]);
          const int vrow = d >> 2, vslot = d & 3;
          gld16(V + (size_t)vrow * S_LEN + kn + ((vslot ^ ((vrow >> 1) & 3)) * 8),
                &Vs[bufi ^ 1][cb * 8]);
        }
        asm volatile("s_waitcnt vmcnt(4)" ::: "memory");  // tile itk landed
      } else {
        asm volatile("s_waitcnt vmcnt(0)" ::: "memory");
      }
      asm volatile("s_barrier" ::: "memory");

      // K fragments from LDS: row = u*16+lr, slot = (kb*4+lg) ^ lr
      bf16x8 kf[2][4];
#pragma unroll
      for (int u = 0; u < 2; ++u)
#pragma unroll
        for (int kb = 0; kb < 4; ++kb)
          kf[u][kb] = *(const bf16x8*)(
              &Ks[bufi][(u * 16 + lr) * 128 + (((kb * 4 + lg) ^ lr) << 3)]);

      f32x4 s[2][2];
#pragma unroll
      for (int t = 0; t < 2; ++t)
#pragma unroll
        for (int u = 0; u < 2; ++u) s[t][u] = (f32x4){0.f, 0.f, 0.f, 0.f};

      __builtin_amdgcn_s_setprio(1);
#pragma unroll
      for (int kb = 0; kb < 4; ++kb) {
        s[0][0] = __builtin_amdgcn_mfma_f32_16x16x32_bf16(kf[0][kb], qf[0][kb], s[0][0], 0, 0, 0);
        s[1][0] = __builtin_amdgcn_mfma_f32_16x16x32_bf16(kf[0][kb], qf[1][kb], s[1][0], 0, 0, 0);
        s[0][1] = __builtin_amdgcn_mfma_f32_16x16x32_bf16(kf[1][kb], qf[0][kb], s[0][1], 0, 0, 0);
        s[1][1] = __builtin_amdgcn_mfma_f32_16x16x32_bf16(kf[1][kb], qf[1][kb], s[1][1], 0, 0, 0);
      }
      __builtin_amdgcn_s_setprio(0);

      if (k0 == q0) {  // causal mask, diagonal tile only
#pragma unroll
        for (int t = 0; t < 2; ++t)
#pragma unroll
          for (int u = 0; u < 2; ++u)
#pragma unroll
            for (int r = 0; r < 4; ++r)
              if (u * 16 + lg * 4 + r > t * 16 + lr) s[t][u][r] = -1e30f;
      }

      float pm[2];
#pragma unroll
      for (int t = 0; t < 2; ++t) {
        float a = fmaxf(fmaxf(s[t][0][0], s[t][0][1]), fmaxf(s[t][0][2], s[t][0][3]));
        float c = fmaxf(fmaxf(s[t][1][0], s[t][1][1]), fmaxf(s[t][1][2], s[t][1][3]));
        pm[t] = fmaxf(a, c);
      }

      if (__any((pm[0] > mi[0] + 8.f) || (pm[1] > mi[1] + 8.f))) {
#pragma unroll
        for (int t = 0; t < 2; ++t) {
          float m = pm[t];
          m = fmaxf(m, __shfl_xor(m, 16));
          m = fmaxf(m, __shfl_xor(m, 32));
          const float mn = fmaxf(mi[t], m);
          const float al = __expf(mi[t] - mn);
          mi[t] = mn;
          lip[t] *= al;
#pragma unroll
          for (int r = 0; r < 4; ++r) {
            const float ar = __shfl(al, lg * 4 + r);
#pragma unroll
            for (int c = 0; c < 8; ++c) o[t][c][r] *= ar;
          }
        }
      }

#pragma unroll
      for (int t = 0; t < 2; ++t) {
        float p[2][4];
#pragma unroll
        for (int u = 0; u < 2; ++u)
#pragma unroll
          for (int r = 0; r < 4; ++r) p[u][r] = __expf(s[t][u][r] - mi[t]);
        lip[t] += ((p[0][0] + p[0][1]) + (p[0][2] + p[0][3])) +
                  ((p[1][0] + p[1][1]) + (p[1][2] + p[1][3]));
#pragma unroll
        for (int u = 0; u < 2; ++u) {
          const uint w0 = cvt_pk_bf16(p[u][0], p[u][1]);
          const uint w1 = cvt_pk_bf16(p[u][2], p[u][3]);
          *(uint2*)(&P[wid][0] + lr * 40 + u * 16 + lg * 4) = make_uint2(w0, w1);
        }
        // A-fragment of P: row=lr, k=lg*8..+7 (in-wave LDS transpose, no barrier)
        const bf16x8 pa = *(const bf16x8*)(&P[wid][0] + lr * 40 + lg * 8);

        // V fragments from LDS: row = c*16+lr, slot = lg ^ ((lr>>1)&3)
        __builtin_amdgcn_s_setprio(1);
#pragma unroll
        for (int c = 0; c < 8; ++c) {
          const bf16x8 vf = *(const bf16x8*)(
              &Vs[bufi][(c * 16 + lr) * 32 + ((lg ^ ((lr >> 1) & 3)) << 3)]);
          o[t][c] = __builtin_amdgcn_mfma_f32_16x16x32_bf16(pa, vf, o[t][c], 0, 0, 0);
        }
        __builtin_amdgcn_s_setprio(0);
      }

      asm volatile("s_barrier" ::: "memory");  // all waves done reading bufi
    }

    float linv[2];
#pragma unroll
    for (int t = 0; t < 2; ++t) {
      float rt = lip[t];
      rt += __shfl_xor(rt, 16);
      rt += __shfl_xor(rt, 32);
      linv[t] = 1.f / rt;
    }
#pragma unroll
    for (int t = 0; t < 2; ++t) {
#pragma unroll
      for (int r = 0; r < 4; ++r) {
        const float ir = __shfl(linv[t], lg * 4 + r);
        const size_t row = (size_t)(b * S_LEN + q0 + t * 16 + lg * 4 + r) * NQKV + h * HD;
#pragma unroll
        for (int c = 0; c < 8; ++c) qkv[row + c * 16 + lr] = f2b(o[t][c][r] * ir);
      }
    }
  }
}

extern "C" void kernel_launch(void* const* d_in, const int* in_sizes, int n_in,
                              void* d_out, int out_size, void* d_ws, size_t ws_size,
                              hipStream_t stream) {
  const float* hidden = (const float*)d_in[1];
  const float* w_qkv  = (const float*)d_in[2];
  const float* w_o    = (const float*)d_in[3];
  float* out = (float*)d_out;
  char* ws = (char*)d_ws;

  // workspace layout (128 MiB):
  // R0 [0, 48 MiB)   : wqkvT bf16 [6144][4096]; after gemm1: Vt bf16 [16][128][2048]
  // R1 [48, 80 MiB)  : hb bf16 [4096][4096];    after gemm1: woT bf16 [4096][4096]
  // R2 [80, 128 MiB) : qkv bf16 [4096][6144]; rope in-place; attn into q slots
  ushort* wqkvT = (ushort*)(ws);
  ushort* Vt    = (ushort*)(ws);
  ushort* hb    = (ushort*)(ws + (48u << 20));
  ushort* woT   = (ushort*)(ws + (48u << 20));
  ushort* qkvb  = (ushort*)(ws + (80u << 20));

  // 1) weight + activation prep
  trans_f32_bf16<<<dim3(192, 128), dim3(32, 8), 0, stream>>>(w_qkv, wqkvT, HID, NQKV);
  cvt_bf16<<<16384, 256, 0, stream>>>(hidden, hb, NB * S_LEN * HID);
  // 2) qkv = hb @ wqkvT^T  (v3: 128x256 block, wave 128x64, ring-2 BK=32)
  gemm_p3<ushort><<<dim3(24, 32), 256, 0, stream>>>(
      hb, wqkvT, qkvb, NB * S_LEN, NQKV, HID, HID, HID);
  // 3) RoPE in-place (q pre-scaled by 1/sqrt(D))
  rope_qk<<<40960, 256, 0, stream>>>(qkvb);
  // 4) V -> Vt[d][s]  (into dead wqkvT region)
  vtrans<<<dim3(4, 64, 16), dim3(32, 8), 0, stream>>>(qkvb, Vt);
  // 5) w_o -> woT (into dead hb region)
  trans_f32_bf16<<<dim3(128, 128), dim3(32, 8), 0, stream>>>(w_o, woT, HID, HID);
  // 6) flash attention v5: paired q-tiles, block-shared LDS K/V double-buffer
  attn_fa<<<dim3(32, 8, 2), 256, 0, stream>>>(qkvb, Vt);
  // 7) out = attn @ woT^T  (v3 gemm)
  gemm_p3<float><<<dim3(16, 32), 256, 0, stream>>>(
      qkvb, woT, out, NB * S_LEN, HID, HID, NQKV, HID);
}